// Round 1
// baseline (124.863 us; speedup 1.0000x reference)
//
#include <hip/hip_runtime.h>

// W_MUL = sqrt(2)/sqrt(5)
#define WMUL 0.63245553203367586640f

struct cplx { float re, im; };

__device__ __forceinline__ cplx cmul(cplx a, cplx b) {
    return { a.re*b.re - a.im*b.im, a.re*b.im + a.im*b.re };
}
__device__ __forceinline__ cplx cmacc(cplx acc, cplx a, cplx b) {
    acc.re += a.re*b.re - a.im*b.im;
    acc.im += a.re*b.im + a.im*b.re;
    return acc;
}
__device__ __forceinline__ cplx cconj(cplx a) { return { a.re, -a.im }; }

// Out = X @ Breal   (X complex 32x32 LDS, Breal real 32x32 global)
__device__ __forceinline__ void mm_realB(const cplx* X, const float* Br, cplx* Out,
                                         int i, int j) {
    cplx acc = {0.f, 0.f};
    #pragma unroll
    for (int k = 0; k < 32; ++k) {
        float b = Br[k*32 + j];
        cplx x = X[i*32 + k];
        acc.re += x.re * b;
        acc.im += x.im * b;
    }
    Out[i*32 + j] = acc;
}

// Out = X @ Y^H
__device__ __forceinline__ void mm_conjT(const cplx* X, const cplx* Y, cplx* Out,
                                         int i, int j) {
    cplx acc = {0.f, 0.f};
    #pragma unroll
    for (int k = 0; k < 32; ++k)
        acc = cmacc(acc, X[i*32 + k], cconj(Y[j*32 + k]));
    Out[i*32 + j] = acc;
}

// Out = X @ Y
__device__ __forceinline__ void mm(const cplx* X, const cplx* Y, cplx* Out,
                                   int i, int j) {
    cplx acc = {0.f, 0.f};
    #pragma unroll
    for (int k = 0; k < 32; ++k)
        acc = cmacc(acc, X[i*32 + k], Y[k*32 + j]);
    Out[i*32 + j] = acc;
}

__global__ __launch_bounds__(1024)
void qmutual_kernel(const float* __restrict__ A, const float* __restrict__ B,
                    const float* __restrict__ weight, float* __restrict__ out,
                    int out_size)
{
    // 64 KB arena, aliased across phases (syncthreads between all reuses):
    //  [0..1023]   LA      -> later N1
    //  [1024..]    LB      -> later N2
    //  [2048..]    L2A
    //  [3072..]    A1      (first 80 entries alias the 20 2x2 gates in phase 1)
    //  [4096..]    B1
    //  [5120..]    A2
    //  [6144..]    B2
    //  [7168..]    T       (first 512 entries alias invp[1024] ints in phase 3)
    __shared__ cplx arena[8192];
    cplx* LA  = arena;
    cplx* LB  = arena + 1024;
    cplx* L2A = arena + 2048;
    cplx* A1  = arena + 3072;
    cplx* B1  = arena + 4096;
    cplx* A2  = arena + 5120;
    cplx* B2  = arena + 6144;
    cplx* T   = arena + 7168;
    cplx* gates = A1;            // [layer(2)][q(10)][2][2] = 80 cplx
    int*  invp  = (int*)T;       // 1024 ints

    const int tid = threadIdx.x;
    const int i = tid >> 5, j = tid & 31;

    // ---- Phase 1a: combined per-qubit gates G = Rz * Ry * Rx ----
    if (tid < 20) {
        const int layer = tid / 10;      // 0 = first layer, 1 = second layer
        const int q     = tid % 10;
        const float w0 = weight[6*q + 3*layer + 0] * WMUL;
        const float w1 = weight[6*q + 3*layer + 1] * WMUL;
        const float w2 = weight[6*q + 3*layer + 2] * WMUL;
        const float cx = cosf(0.5f*w0), sx = sinf(0.5f*w0);
        const float cy = cosf(0.5f*w1), sy = sinf(0.5f*w1);
        const float cz = cosf(0.5f*w2), sz = sinf(0.5f*w2);
        // Rx = [[cx, -i sx], [-i sx, cx]]
        cplx rx[2][2] = { { {cx,0.f}, {0.f,-sx} }, { {0.f,-sx}, {cx,0.f} } };
        // Ry = [[cy, -sy], [sy, cy]]
        cplx ry[2][2] = { { {cy,0.f}, {-sy,0.f} }, { {sy,0.f}, {cy,0.f} } };
        // Rz = diag(cz - i sz, cz + i sz)
        const cplx rz0 = {cz, -sz}, rz1 = {cz, sz};
        cplx m[2][2];
        #pragma unroll
        for (int r = 0; r < 2; ++r)
            #pragma unroll
            for (int c = 0; c < 2; ++c)
                m[r][c] = cmacc(cmul(ry[r][0], rx[0][c]), ry[r][1], rx[1][c]);
        cplx* g = gates + (layer*10 + q)*4;
        g[0] = cmul(rz0, m[0][0]); g[1] = cmul(rz0, m[0][1]);
        g[2] = cmul(rz1, m[1][0]); g[3] = cmul(rz1, m[1][1]);
    }
    __syncthreads();

    // ---- Phase 1b: Kronecker products (qubit 0 most significant) ----
    {
        cplx la = {1.f,0.f}, lb = {1.f,0.f}, l2a = {1.f,0.f};
        #pragma unroll
        for (int qq = 0; qq < 5; ++qq) {
            const int rb = (i >> (4 - qq)) & 1;
            const int cb = (j >> (4 - qq)) & 1;
            la  = cmul(la,  gates[(0*10 + qq    )*4 + rb*2 + cb]);
            lb  = cmul(lb,  gates[(0*10 + 5 + qq)*4 + rb*2 + cb]);
            l2a = cmul(l2a, gates[(1*10 + qq    )*4 + rb*2 + cb]);
        }
        LA[tid] = la; LB[tid] = lb; L2A[tid] = l2a;
    }
    __syncthreads();

    // ---- Phase 2: conjugations A1=LA A LA^H, B1=LB B LB^H, A2=LA B LA^H, B2=LB A LB^H
    mm_realB(LA, A, T, i, j);  __syncthreads();
    mm_conjT(T, LA, A1, i, j); __syncthreads();
    mm_realB(LB, B, T, i, j);  __syncthreads();
    mm_conjT(T, LB, B1, i, j); __syncthreads();
    mm_realB(LA, B, T, i, j);  __syncthreads();
    mm_conjT(T, LA, A2, i, j); __syncthreads();
    mm_realB(LB, A, T, i, j);  __syncthreads();
    mm_conjT(T, LB, B2, i, j); __syncthreads();

    // ---- Phase 3a: inverse CNOT-chain permutation ----
    // forward: for q=0..8: if bit q set flip bit q+1; then if bit 9 set flip bit 0.
    // bit q of x lives at shift (9-q)  (qubit 0 = MSB).
    {
        int x = tid;
        if (x & 1) x ^= (1 << 9);                 // undo CNOT(9,0)
        #pragma unroll
        for (int q = 8; q >= 0; --q)
            if ((x >> (9 - q)) & 1) x ^= (1 << (8 - q));   // undo CNOT(q,q+1)
        invp[tid] = x;
    }
    __syncthreads();

    // ---- Phase 3b: N1[k,k'] = sum_kB A1[a(l),a(l')] * B1[b(l),b(l')], l=invp[(k<<5)|kB]
    {
        cplx acc1 = {0.f,0.f}, acc2 = {0.f,0.f};
        #pragma unroll
        for (int kb = 0; kb < 32; ++kb) {
            const int l  = invp[(i << 5) | kb];
            const int l2 = invp[(j << 5) | kb];
            const int ia = (l >> 5)*32 + (l2 >> 5);
            const int ib = (l & 31)*32 + (l2 & 31);
            acc1 = cmacc(acc1, A1[ia], B1[ib]);
            acc2 = cmacc(acc2, A2[ia], B2[ib]);
        }
        LA[tid] = acc1;   // N1 reuses LA storage
        LB[tid] = acc2;   // N2 reuses LB storage
    }
    __syncthreads();

    // ---- Phase 4: results R = L2A @ N @ L2A^H ----
    cplx* N1 = LA;
    cplx* N2 = LB;

    mm(L2A, N1, T, i, j); __syncthreads();
    {
        cplx acc = {0.f,0.f};
        #pragma unroll
        for (int k = 0; k < 32; ++k)
            acc = cmacc(acc, T[i*32 + k], cconj(L2A[j*32 + k]));
        if (out_size >= 4096) { out[2*tid] = acc.re; out[2*tid + 1] = acc.im; }
        else                  { out[tid] = acc.re; }
    }
    __syncthreads();

    mm(L2A, N2, T, i, j); __syncthreads();
    {
        cplx acc = {0.f,0.f};
        #pragma unroll
        for (int k = 0; k < 32; ++k)
            acc = cmacc(acc, T[i*32 + k], cconj(L2A[j*32 + k]));
        if (out_size >= 4096) { out[2048 + 2*tid] = acc.re; out[2048 + 2*tid + 1] = acc.im; }
        else                  { out[1024 + tid] = acc.re; }
    }
}

extern "C" void kernel_launch(void* const* d_in, const int* in_sizes, int n_in,
                              void* d_out, int out_size, void* d_ws, size_t ws_size,
                              hipStream_t stream) {
    const float* A = (const float*)d_in[0];   // inputA 32x32 fp32
    const float* B = (const float*)d_in[1];   // inputB 32x32 fp32
    const float* w = (const float*)d_in[2];   // weight 60 fp32
    float* out = (float*)d_out;
    qmutual_kernel<<<1, 1024, 0, stream>>>(A, B, w, out, out_size);
}

// Round 2
// 74.881 us; speedup vs baseline: 1.6675x; 1.6675x over previous
//
#include <hip/hip_runtime.h>

// W_MUL = sqrt(2)/sqrt(5)
#define WMUL 0.63245553203367586640f

struct cplx { float re, im; };

__device__ __forceinline__ cplx cmul(cplx a, cplx b) {
    return { a.re*b.re - a.im*b.im, a.re*b.im + a.im*b.re };
}
__device__ __forceinline__ cplx cmacc(cplx acc, cplx a, cplx b) {
    acc.re += a.re*b.re - a.im*b.im;
    acc.im += a.re*b.im + a.im*b.re;
    return acc;
}

// LDS layout (cplx units), 7744 cplx = 60.5 KB:
//   CLA   [0    .. 1023]  CLA[k*32+j] = conj(LA[j][k])
//   CLB   [1024 .. 2047]
//   CL2A  [2048 .. 3071]
//   TA    [3072 .. 4095]  (later N)
//   TB    [4096 .. 5119]  (later TF)
//   A1p   [5120 .. 6175]  stride-33 padded (first 80 alias gates in phase 1)
//   B1p   [6176 .. 7231]  stride-33 padded
//   invpT [7232 .. 7743]  1024 ints
__global__ __launch_bounds__(1024)
void qmutual_kernel(const float* __restrict__ A, const float* __restrict__ B,
                    const float* __restrict__ weight, float* __restrict__ out,
                    int out_size)
{
    __shared__ cplx arena[7744];
    cplx* CLA   = arena;
    cplx* CLB   = arena + 1024;
    cplx* CL2A  = arena + 2048;
    cplx* TA    = arena + 3072;
    cplx* TB    = arena + 4096;
    cplx* A1p   = arena + 5120;   // row stride 33
    cplx* B1p   = arena + 6176;   // row stride 33
    int*  invpT = (int*)(arena + 7232);
    cplx* gates = A1p;            // [layer(2)][q(10)][2][2] = 80 cplx, dead after phase 2

    const int tid = threadIdx.x;
    const int i = tid >> 5, j = tid & 31;
    const int blk = blockIdx.x;
    const float* MA = blk ? B : A;   // block 0: A(x)B path, block 1: B(x)A path
    const float* MB = blk ? A : B;

    // ---- Phase 1: combined per-qubit gates G = Rz * Ry * Rx ----
    if (tid < 20) {
        const int layer = tid / 10;
        const int q     = tid % 10;
        const float w0 = weight[6*q + 3*layer + 0] * WMUL;
        const float w1 = weight[6*q + 3*layer + 1] * WMUL;
        const float w2 = weight[6*q + 3*layer + 2] * WMUL;
        const float cx = cosf(0.5f*w0), sx = sinf(0.5f*w0);
        const float cy = cosf(0.5f*w1), sy = sinf(0.5f*w1);
        const float cz = cosf(0.5f*w2), sz = sinf(0.5f*w2);
        cplx rx[2][2] = { { {cx,0.f}, {0.f,-sx} }, { {0.f,-sx}, {cx,0.f} } };
        cplx ry[2][2] = { { {cy,0.f}, {-sy,0.f} }, { {sy,0.f}, {cy,0.f} } };
        const cplx rz0 = {cz, -sz}, rz1 = {cz, sz};
        cplx m[2][2];
        #pragma unroll
        for (int r = 0; r < 2; ++r)
            #pragma unroll
            for (int c = 0; c < 2; ++c)
                m[r][c] = cmacc(cmul(ry[r][0], rx[0][c]), ry[r][1], rx[1][c]);
        cplx* g = gates + (layer*10 + q)*4;
        g[0] = cmul(rz0, m[0][0]); g[1] = cmul(rz0, m[0][1]);
        g[2] = cmul(rz1, m[1][0]); g[3] = cmul(rz1, m[1][1]);
    }
    __syncthreads();

    // ---- Phase 2: conj-transposed Kroneckers + transposed inverse permutation ----
    {
        // element (row=j, col=i) of each kron, then conjugate -> CX[k=i.. wait:
        // CLA[i*32+j] := conj(LA[j][i])  (thread writes at tid, stride-1)
        cplx la = {1.f,0.f}, lb = {1.f,0.f}, l2a = {1.f,0.f};
        #pragma unroll
        for (int qq = 0; qq < 5; ++qq) {
            const int rb = (j >> (4 - qq)) & 1;   // row bits from j (transposed)
            const int cb = (i >> (4 - qq)) & 1;   // col bits from i
            la   = cmul(la,   gates[(qq     )*4 + rb*2 + cb]);
            lb   = cmul(lb,   gates[(5 + qq )*4 + rb*2 + cb]);
            l2a  = cmul(l2a,  gates[(10 + qq)*4 + rb*2 + cb]);
        }
        CLA[tid]  = { la.re,  -la.im  };
        CLB[tid]  = { lb.re,  -lb.im  };
        CL2A[tid] = { l2a.re, -l2a.im };

        // invpT[kb*32 + k] = inverse-perm((k<<5)|kb); tid = kb*32 + k
        const int k  = tid & 31;
        const int kb = tid >> 5;
        int x = (k << 5) | kb;
        if (x & 1) x ^= (1 << 9);                 // undo CNOT(9,0)
        #pragma unroll
        for (int q = 8; q >= 0; --q)
            if ((x >> (9 - q)) & 1) x ^= (1 << (8 - q));   // undo CNOT(q,q+1)
        invpT[tid] = x;
    }
    __syncthreads();

    // ---- Phase 3: TA = LA @ MA, TB = LB @ MB  (LA[i][k] = conj(CLA[k][i])) ----
    {
        cplx ta = {0.f,0.f}, tb = {0.f,0.f};
        #pragma unroll
        for (int k = 0; k < 32; ++k) {
            const float a_ = MA[k*32 + j];        // global, coalesced, L1-hot
            const float b_ = MB[k*32 + j];
            const cplx xa = CLA[k*32 + i];        // row-broadcast
            const cplx xb = CLB[k*32 + i];
            ta.re += xa.re * a_;  ta.im -= xa.im * a_;
            tb.re += xb.re * b_;  tb.im -= xb.im * b_;
        }
        TA[tid] = ta; TB[tid] = tb;
    }
    __syncthreads();

    // ---- Phase 4: A1 = TA @ LA^H, B1 = TB @ LB^H  (conj(LA[j][k]) = CLA[k][j]) ----
    {
        cplx a1 = {0.f,0.f}, b1 = {0.f,0.f};
        #pragma unroll
        for (int k = 0; k < 32; ++k) {
            a1 = cmacc(a1, TA[i*32 + k], CLA[k*32 + j]);   // broadcast x stride-1
            b1 = cmacc(b1, TB[i*32 + k], CLB[k*32 + j]);
        }
        A1p[i*33 + j] = a1;       // gates region is dead now
        B1p[i*33 + j] = b1;
    }
    __syncthreads();

    // ---- Phase 5: permutation gather + partial trace ----
    // N[k][k'] = sum_kb A1[l>>5][l2>>5] * B1[l&31][l2&31], l=invp[(k<<5)|kb]
    {
        cplx n = {0.f,0.f};
        #pragma unroll
        for (int kb = 0; kb < 32; ++kb) {
            const int l  = invpT[kb*32 + i];      // broadcast
            const int l2 = invpT[kb*32 + j];      // stride-1
            n = cmacc(n, A1p[(l >> 5)*33 + (l2 >> 5)],
                         B1p[(l & 31)*33 + (l2 & 31)]);
        }
        TA[tid] = n;              // N reuses TA (no reader of TA in this phase)
    }
    __syncthreads();

    // ---- Phase 6: TF = L2A @ N  (L2A[i][k] = conj(CL2A[k][i])) ----
    cplx* N  = TA;
    cplx* TF = TB;
    {
        cplx tf = {0.f,0.f};
        #pragma unroll
        for (int k = 0; k < 32; ++k) {
            const cplx x = CL2A[k*32 + i];        // broadcast; L2A[i][k] = conj(x)
            const cplx nk = N[k*32 + j];          // stride-1
            tf.re += x.re*nk.re + x.im*nk.im;
            tf.im += x.re*nk.im - x.im*nk.re;
        }
        TF[tid] = tf;
    }
    __syncthreads();

    // ---- Phase 7: R = TF @ L2A^H, store ----
    {
        cplx r = {0.f,0.f};
        #pragma unroll
        for (int k = 0; k < 32; ++k)
            r = cmacc(r, TF[i*32 + k], CL2A[k*32 + j]);
        if (out_size >= 4096) {
            out[blk*2048 + 2*tid]     = r.re;
            out[blk*2048 + 2*tid + 1] = r.im;
        } else {
            out[blk*1024 + tid] = r.re;
        }
    }
}

extern "C" void kernel_launch(void* const* d_in, const int* in_sizes, int n_in,
                              void* d_out, int out_size, void* d_ws, size_t ws_size,
                              hipStream_t stream) {
    const float* A = (const float*)d_in[0];   // inputA 32x32 fp32
    const float* B = (const float*)d_in[1];   // inputB 32x32 fp32
    const float* w = (const float*)d_in[2];   // weight 60 fp32
    float* out = (float*)d_out;
    qmutual_kernel<<<2, 1024, 0, stream>>>(A, B, w, out, out_size);
}

// Round 3
// 74.859 us; speedup vs baseline: 1.6680x; 1.0003x over previous
//
#include <hip/hip_runtime.h>

// W_MUL = sqrt(2)/sqrt(5)
#define WMUL 0.63245553203367586640f

struct cplx { float re, im; };
struct __align__(16) cplx2 { cplx a, b; };

__device__ __forceinline__ cplx cmul(cplx a, cplx b) {
    return { a.re*b.re - a.im*b.im, a.re*b.im + a.im*b.re };
}
__device__ __forceinline__ cplx cmacc(cplx acc, cplx a, cplx b) {
    acc.re += a.re*b.re - a.im*b.im;
    acc.im += a.re*b.im + a.im*b.re;
    return acc;
}

// 256 threads, per-thread 2x2 tile (rows {2i0,2i0+1}, cols {2j0,2j0+1}).
// LDS arena (cplx units, 58.9 KB):
//   CLA  [0   ..1023]  [k*32+j] = conj(LA[j][k])
//   CLB  [1024..2047]
//   CL2A [2048..3071]
//   TAT  [3072..4159]  [j*34+i] = TA[i][j]   (pad 34)
//   TBT  [4160..5247]
//   A1p  [5248..6303]  [r*33+c]              (pad 33; head aliases gates[80])
//   B1p  [6304..7359]
//   Np   aliases [0..1087]   [k*34+c]  (CLA/CLB dead after P4)
//   TFT  aliases [3072..4159] [j*34+i] (TAT dead after P4)
__global__ __launch_bounds__(256)
void qmutual_kernel(const float* __restrict__ A, const float* __restrict__ B,
                    const float* __restrict__ weight, float* __restrict__ out,
                    int out_size)
{
    __shared__ __align__(16) cplx arena[7360];
    cplx* CLA   = arena;
    cplx* CLB   = arena + 1024;
    cplx* CL2A  = arena + 2048;
    cplx* TAT   = arena + 3072;
    cplx* TBT   = arena + 4160;
    cplx* A1p   = arena + 5248;
    cplx* B1p   = arena + 6304;
    cplx* Np    = arena;
    cplx* TFT   = arena + 3072;
    cplx* gates = arena + 5248;   // [layer*10+q][2][2], 80 cplx

    const int tid = threadIdx.x;
    const int i0 = tid >> 4, j0 = tid & 15;
    const int r0 = 2*i0, c0 = 2*j0;
    const int blk = blockIdx.x;
    const float* MA = blk ? B : A;   // block 0: A(x)B path, block 1: B(x)A path
    const float* MB = blk ? A : B;

    // ---- P1: combined per-qubit gates G = Rz*Ry*Rx ----
    if (tid < 20) {
        const int layer = tid / 10, q = tid % 10;
        const float w0 = weight[6*q + 3*layer + 0] * WMUL;
        const float w1 = weight[6*q + 3*layer + 1] * WMUL;
        const float w2 = weight[6*q + 3*layer + 2] * WMUL;
        const float cx = cosf(0.5f*w0), sx = sinf(0.5f*w0);
        const float cy = cosf(0.5f*w1), sy = sinf(0.5f*w1);
        const float cz = cosf(0.5f*w2), sz = sinf(0.5f*w2);
        cplx rx[2][2] = { { {cx,0.f}, {0.f,-sx} }, { {0.f,-sx}, {cx,0.f} } };
        cplx ry[2][2] = { { {cy,0.f}, {-sy,0.f} }, { {sy,0.f}, {cy,0.f} } };
        const cplx rz0 = {cz, -sz}, rz1 = {cz, sz};
        cplx m[2][2];
        #pragma unroll
        for (int r = 0; r < 2; ++r)
            #pragma unroll
            for (int c = 0; c < 2; ++c)
                m[r][c] = cmacc(cmul(ry[r][0], rx[0][c]), ry[r][1], rx[1][c]);
        cplx* g = gates + tid*4;
        g[0] = cmul(rz0, m[0][0]); g[1] = cmul(rz0, m[0][1]);
        g[2] = cmul(rz1, m[1][0]); g[3] = cmul(rz1, m[1][1]);
    }
    __syncthreads();

    // ---- P2: build conj-Kronecker matrices, 4 entries/thread each ----
    {
        cplx vals[3][2][2];
        #pragma unroll
        for (int mat = 0; mat < 3; ++mat) {
            const int gbase = (mat == 0) ? 0 : (mat == 1 ? 5 : 10);
            #pragma unroll
            for (int kk = 0; kk < 2; ++kk)
                #pragma unroll
                for (int jj = 0; jj < 2; ++jj) {
                    const int k = r0 + kk, j = c0 + jj;
                    cplx v = {1.f, 0.f};
                    #pragma unroll
                    for (int q = 0; q < 5; ++q) {
                        const int rb = (j >> (4-q)) & 1;
                        const int cb = (k >> (4-q)) & 1;
                        v = cmul(v, gates[(gbase+q)*4 + rb*2 + cb]);
                    }
                    vals[mat][kk][jj] = { v.re, -v.im };   // conj
                }
        }
        #pragma unroll
        for (int kk = 0; kk < 2; ++kk) {
            *(cplx2*)&CLA [(r0+kk)*32 + c0] = { vals[0][kk][0], vals[0][kk][1] };
            *(cplx2*)&CLB [(r0+kk)*32 + c0] = { vals[1][kk][0], vals[1][kk][1] };
            *(cplx2*)&CL2A[(r0+kk)*32 + c0] = { vals[2][kk][0], vals[2][kk][1] };
        }
    }
    __syncthreads();

    // ---- P3: TA = LA @ MA, TB = LB @ MB (MA,MB real, global/L1) ----
    {
        cplx ta[2][2] = {}, tb[2][2] = {};
        #pragma unroll
        for (int k = 0; k < 32; ++k) {
            const cplx2 xa = *(const cplx2*)&CLA[k*32 + r0];  // conj(LA[r0/r1][k])
            const cplx2 xb = *(const cplx2*)&CLB[k*32 + r0];
            const float2 ma = *(const float2*)&MA[k*32 + c0];
            const float2 mb = *(const float2*)&MB[k*32 + c0];
            ta[0][0].re += xa.a.re*ma.x; ta[0][0].im -= xa.a.im*ma.x;
            ta[0][1].re += xa.a.re*ma.y; ta[0][1].im -= xa.a.im*ma.y;
            ta[1][0].re += xa.b.re*ma.x; ta[1][0].im -= xa.b.im*ma.x;
            ta[1][1].re += xa.b.re*ma.y; ta[1][1].im -= xa.b.im*ma.y;
            tb[0][0].re += xb.a.re*mb.x; tb[0][0].im -= xb.a.im*mb.x;
            tb[0][1].re += xb.a.re*mb.y; tb[0][1].im -= xb.a.im*mb.y;
            tb[1][0].re += xb.b.re*mb.x; tb[1][0].im -= xb.b.im*mb.x;
            tb[1][1].re += xb.b.re*mb.y; tb[1][1].im -= xb.b.im*mb.y;
        }
        #pragma unroll
        for (int g = 0; g < 2; ++g) {
            *(cplx2*)&TAT[(c0+g)*34 + r0] = { ta[0][g], ta[1][g] };
            *(cplx2*)&TBT[(c0+g)*34 + r0] = { tb[0][g], tb[1][g] };
        }
    }
    __syncthreads();

    // ---- P4: A1 = TA @ LA^H, B1 = TB @ LB^H ----
    {
        cplx a1[2][2] = {}, b1[2][2] = {};
        #pragma unroll
        for (int k = 0; k < 32; ++k) {
            const cplx2 t  = *(const cplx2*)&TAT[k*34 + r0];  // TA[r0/r1][k] (bcast)
            const cplx2 u  = *(const cplx2*)&TBT[k*34 + r0];
            const cplx2 ca = *(const cplx2*)&CLA[k*32 + c0];  // conj(LA[c0/c1][k])
            const cplx2 cb = *(const cplx2*)&CLB[k*32 + c0];
            a1[0][0] = cmacc(a1[0][0], t.a, ca.a); a1[0][1] = cmacc(a1[0][1], t.a, ca.b);
            a1[1][0] = cmacc(a1[1][0], t.b, ca.a); a1[1][1] = cmacc(a1[1][1], t.b, ca.b);
            b1[0][0] = cmacc(b1[0][0], u.a, cb.a); b1[0][1] = cmacc(b1[0][1], u.a, cb.b);
            b1[1][0] = cmacc(b1[1][0], u.b, cb.a); b1[1][1] = cmacc(b1[1][1], u.b, cb.b);
        }
        #pragma unroll
        for (int p = 0; p < 2; ++p)
            #pragma unroll
            for (int g = 0; g < 2; ++g) {
                A1p[(r0+p)*33 + c0+g] = a1[p][g];
                B1p[(r0+p)*33 + c0+g] = b1[p][g];
            }
    }
    __syncthreads();

    // ---- P5: permutation gather + partial trace (closed-form GF(2) indices) ----
    // invp((k<<5)|kb): hi5 = G(k) ^ (kb&1 ? 24 : 0), lo5 = ((k&1)<<4) ^ G(kb),
    // with G(x) = x ^ (x>>1).  B1 indices are wave-uniform literals.
    {
        const int gr0 = r0 ^ (r0 >> 1), gr1 = (r0+1) ^ ((r0+1) >> 1);
        const int gc0 = c0 ^ (c0 >> 1), gc1 = (c0+1) ^ ((c0+1) >> 1);
        cplx n[2][2] = {};
        #pragma unroll
        for (int kb = 0; kb < 32; ++kb) {
            const int t24 = (kb & 1) ? 24 : 0;      // compile-time
            const int g   = kb ^ (kb >> 1);         // compile-time
            const int ar0 = gr0 ^ t24, ar1 = gr1 ^ t24;
            const int ac0 = gc0 ^ t24, ac1 = gc1 ^ t24;
            const cplx A00 = A1p[ar0*33 + ac0], A01 = A1p[ar0*33 + ac1];
            const cplx A10 = A1p[ar1*33 + ac0], A11 = A1p[ar1*33 + ac1];
            const cplx B00 = B1p[g*33 + g],          B01 = B1p[g*33 + (16^g)];
            const cplx B10 = B1p[(16^g)*33 + g],     B11 = B1p[(16^g)*33 + (16^g)];
            n[0][0] = cmacc(n[0][0], A00, B00); n[0][1] = cmacc(n[0][1], A01, B01);
            n[1][0] = cmacc(n[1][0], A10, B10); n[1][1] = cmacc(n[1][1], A11, B11);
        }
        __syncthreads();   // all reads of A1p/B1p (and aliased CLA/CLB) done
        #pragma unroll
        for (int p = 0; p < 2; ++p)
            *(cplx2*)&Np[(r0+p)*34 + c0] = { n[p][0], n[p][1] };
    }
    __syncthreads();

    // ---- P6: TF = L2A @ N  (L2A[i][k] = conj(CL2A[k*32+i])) ----
    {
        cplx tf[2][2] = {};
        #pragma unroll
        for (int k = 0; k < 32; ++k) {
            const cplx2 x = *(const cplx2*)&CL2A[k*32 + r0];  // conj(L2A[r0/r1][k])
            const cplx2 m = *(const cplx2*)&Np[k*34 + c0];    // N[k][c0/c1]
            tf[0][0].re += x.a.re*m.a.re + x.a.im*m.a.im;
            tf[0][0].im += x.a.re*m.a.im - x.a.im*m.a.re;
            tf[0][1].re += x.a.re*m.b.re + x.a.im*m.b.im;
            tf[0][1].im += x.a.re*m.b.im - x.a.im*m.b.re;
            tf[1][0].re += x.b.re*m.a.re + x.b.im*m.a.im;
            tf[1][0].im += x.b.re*m.a.im - x.b.im*m.a.re;
            tf[1][1].re += x.b.re*m.b.re + x.b.im*m.b.im;
            tf[1][1].im += x.b.re*m.b.im - x.b.im*m.b.re;
        }
        __syncthreads();   // Np reads done before TFT overwrites nothing aliased w/ Np
        #pragma unroll
        for (int g = 0; g < 2; ++g)
            *(cplx2*)&TFT[(c0+g)*34 + r0] = { tf[0][g], tf[1][g] };
    }
    __syncthreads();

    // ---- P7: R = TF @ L2A^H, store ----
    {
        cplx rr[2][2] = {};
        #pragma unroll
        for (int k = 0; k < 32; ++k) {
            const cplx2 t  = *(const cplx2*)&TFT[k*34 + r0];   // TF[r0/r1][k] (bcast)
            const cplx2 c2 = *(const cplx2*)&CL2A[k*32 + c0];  // conj(L2A[c0/c1][k])
            rr[0][0] = cmacc(rr[0][0], t.a, c2.a); rr[0][1] = cmacc(rr[0][1], t.a, c2.b);
            rr[1][0] = cmacc(rr[1][0], t.b, c2.a); rr[1][1] = cmacc(rr[1][1], t.b, c2.b);
        }
        if (out_size >= 4096) {
            #pragma unroll
            for (int p = 0; p < 2; ++p) {
                float4 v = { rr[p][0].re, rr[p][0].im, rr[p][1].re, rr[p][1].im };
                *(float4*)&out[blk*2048 + (r0+p)*64 + 4*j0] = v;
            }
        } else {
            #pragma unroll
            for (int p = 0; p < 2; ++p) {
                float2 v = { rr[p][0].re, rr[p][1].re };
                *(float2*)&out[blk*1024 + (r0+p)*32 + c0] = v;
            }
        }
    }
}

extern "C" void kernel_launch(void* const* d_in, const int* in_sizes, int n_in,
                              void* d_out, int out_size, void* d_ws, size_t ws_size,
                              hipStream_t stream) {
    const float* A = (const float*)d_in[0];   // inputA 32x32 fp32
    const float* B = (const float*)d_in[1];   // inputB 32x32 fp32
    const float* w = (const float*)d_in[2];   // weight 60 fp32
    float* out = (float*)d_out;
    qmutual_kernel<<<2, 256, 0, stream>>>(A, B, w, out, out_size);
}

// Round 4
// 66.752 us; speedup vs baseline: 1.8705x; 1.1215x over previous
//
#include <hip/hip_runtime.h>

// W_MUL = sqrt(2)/sqrt(5)
#define WMUL 0.63245553203367586640f

typedef float v2f __attribute__((ext_vector_type(2)));   // (re, im)
typedef float v4f __attribute__((ext_vector_type(4)));   // two cplx

__device__ __forceinline__ v4f cat(v2f a, v2f b) { return __builtin_shufflevector(a, b, 0, 1, 2, 3); }
__device__ __forceinline__ v2f lo2(v4f t) { return __builtin_shufflevector(t, t, 0, 1); }
__device__ __forceinline__ v2f hi2(v4f t) { return __builtin_shufflevector(t, t, 2, 3); }

// ---- cold-path C complex math ----
__device__ __forceinline__ v2f cmul_c(v2f a, v2f b) {
    v2f r = { a.x*b.x - a.y*b.y, a.x*b.y + a.y*b.x };
    return r;
}
__device__ __forceinline__ v2f cmacc_c(v2f acc, v2f a, v2f b) {
    acc.x += a.x*b.x - a.y*b.y;
    acc.y += a.x*b.y + a.y*b.x;
    return acc;
}

// ---- hot-path packed complex MACs (2 instrs instead of 4) ----
// d += a*b:  lo += a.re*b.re - a.im*b.im ; hi += a.re*b.im + a.im*b.re
__device__ __forceinline__ void cmacc_pk(v2f& d, v2f a, v2f b) {
    asm("v_pk_fma_f32 %0, %1, %2, %0 op_sel_hi:[0,1,1]\n\t"
        "v_pk_fma_f32 %0, %1, %2, %0 op_sel:[1,1,0] op_sel_hi:[1,0,1] neg_lo:[1,0,0]"
        : "+v"(d) : "v"(a), "v"(b));
}
// d += conj(a)*b: lo += a.re*b.re + a.im*b.im ; hi += a.re*b.im - a.im*b.re
__device__ __forceinline__ void cmacc_cj_pk(v2f& d, v2f a, v2f b) {
    asm("v_pk_fma_f32 %0, %1, %2, %0 op_sel_hi:[0,1,1]\n\t"
        "v_pk_fma_f32 %0, %1, %2, %0 op_sel:[1,1,0] op_sel_hi:[1,0,1] neg_hi:[1,0,0]"
        : "+v"(d) : "v"(a), "v"(b));
}
// d += conj(a)*m, m real duplicated in both halves: lo += a.re*m ; hi += -a.im*m
__device__ __forceinline__ void cmacc_rj_pk(v2f& d, v2f a, v2f m) {
    asm("v_pk_fma_f32 %0, %1, %2, %0 neg_hi:[1,0,0]"
        : "+v"(d) : "v"(a), "v"(m));
}

// 256 threads, per-thread 2x2 tile (rows {2i0,2i0+1}, cols {2j0,2j0+1}).
// LDS arena (v2f units, 58.9 KB):
//   CLA  [0   ..1023]  [k*32+j] = conj(LA[j][k])
//   CLB  [1024..2047]
//   CL2A [2048..3071]
//   TAT  [3072..4159]  [j*34+i] = TA[i][j]   (pad 34)
//   TBT  [4160..5247]
//   A1p  [5248..6303]  [r*33+c]              (pad 33; head aliases gates[80])
//   B1p  [6304..7359]
//   Sarr aliases [3072..3079] (TAT dead after P4)
//   Np   aliases [0..1087]    (CLA/CLB dead after P4)
//   TFT  aliases [3072..4159] (Sarr dead after P5b)
__global__ __launch_bounds__(256)
void qmutual_kernel(const float* __restrict__ A, const float* __restrict__ B,
                    const float* __restrict__ weight, float* __restrict__ out,
                    int out_size)
{
    __shared__ __align__(16) v2f arena[7360];
    v2f* CLA   = arena;
    v2f* CLB   = arena + 1024;
    v2f* CL2A  = arena + 2048;
    v2f* TAT   = arena + 3072;
    v2f* TBT   = arena + 4160;
    v2f* A1p   = arena + 5248;
    v2f* B1p   = arena + 6304;
    v2f* Sarr  = arena + 3072;
    v2f* Np    = arena;
    v2f* TFT   = arena + 3072;
    v2f* gates = arena + 5248;   // [layer*10+q][2][2], 80 cplx, dead after P2

    const int tid = threadIdx.x;
    const int i0 = tid >> 4, j0 = tid & 15;
    const int r0 = 2*i0, c0 = 2*j0;
    const int blk = blockIdx.x;
    const float* MA = blk ? B : A;   // block 0: A(x)B path, block 1: B(x)A path
    const float* MB = blk ? A : B;

    // ---- P1: combined per-qubit gates G = Rz*Ry*Rx ----
    if (tid < 20) {
        const int layer = tid / 10, q = tid % 10;
        const float w0 = weight[6*q + 3*layer + 0] * WMUL;
        const float w1 = weight[6*q + 3*layer + 1] * WMUL;
        const float w2 = weight[6*q + 3*layer + 2] * WMUL;
        const float cx = cosf(0.5f*w0), sx = sinf(0.5f*w0);
        const float cy = cosf(0.5f*w1), sy = sinf(0.5f*w1);
        const float cz = cosf(0.5f*w2), sz = sinf(0.5f*w2);
        v2f rx[2][2] = { { {cx,0.f}, {0.f,-sx} }, { {0.f,-sx}, {cx,0.f} } };
        v2f ry[2][2] = { { {cy,0.f}, {-sy,0.f} }, { {sy,0.f}, {cy,0.f} } };
        const v2f rz0 = {cz, -sz}, rz1 = {cz, sz};
        v2f m[2][2];
        #pragma unroll
        for (int r = 0; r < 2; ++r)
            #pragma unroll
            for (int c = 0; c < 2; ++c)
                m[r][c] = cmacc_c(cmul_c(ry[r][0], rx[0][c]), ry[r][1], rx[1][c]);
        v2f* g = gates + tid*4;
        g[0] = cmul_c(rz0, m[0][0]); g[1] = cmul_c(rz0, m[0][1]);
        g[2] = cmul_c(rz1, m[1][0]); g[3] = cmul_c(rz1, m[1][1]);
    }
    __syncthreads();

    // ---- P2: build conj-Kronecker matrices, 4 entries/thread each ----
    {
        v2f vals[3][2][2];
        #pragma unroll
        for (int mat = 0; mat < 3; ++mat) {
            const int gbase = (mat == 0) ? 0 : (mat == 1 ? 5 : 10);
            #pragma unroll
            for (int kk = 0; kk < 2; ++kk)
                #pragma unroll
                for (int jj = 0; jj < 2; ++jj) {
                    const int k = r0 + kk, j = c0 + jj;
                    v2f v = {1.f, 0.f};
                    #pragma unroll
                    for (int q = 0; q < 5; ++q) {
                        const int rb = (j >> (4-q)) & 1;
                        const int cb = (k >> (4-q)) & 1;
                        v = cmul_c(v, gates[(gbase+q)*4 + rb*2 + cb]);
                    }
                    v2f cv = { v.x, -v.y };
                    vals[mat][kk][jj] = cv;
                }
        }
        #pragma unroll
        for (int kk = 0; kk < 2; ++kk) {
            *(v4f*)&CLA [(r0+kk)*32 + c0] = cat(vals[0][kk][0], vals[0][kk][1]);
            *(v4f*)&CLB [(r0+kk)*32 + c0] = cat(vals[1][kk][0], vals[1][kk][1]);
            *(v4f*)&CL2A[(r0+kk)*32 + c0] = cat(vals[2][kk][0], vals[2][kk][1]);
        }
    }
    __syncthreads();

    // ---- P3: TA = LA @ MA, TB = LB @ MB (MA,MB real; conj(CLA)=LA) ----
    {
        v2f ta[2][2] = {}, tb[2][2] = {};
        #pragma unroll
        for (int k = 0; k < 32; ++k) {
            const v4f xa = *(const v4f*)&CLA[k*32 + r0];
            const v4f xb = *(const v4f*)&CLB[k*32 + r0];
            const float2 ma = *(const float2*)&MA[k*32 + c0];
            const float2 mb = *(const float2*)&MB[k*32 + c0];
            const v2f xa0 = lo2(xa), xa1 = hi2(xa);
            const v2f xb0 = lo2(xb), xb1 = hi2(xb);
            const v2f mx = {ma.x, ma.x}, my = {ma.y, ma.y};
            const v2f nx = {mb.x, mb.x}, ny = {mb.y, mb.y};
            cmacc_rj_pk(ta[0][0], xa0, mx); cmacc_rj_pk(ta[0][1], xa0, my);
            cmacc_rj_pk(ta[1][0], xa1, mx); cmacc_rj_pk(ta[1][1], xa1, my);
            cmacc_rj_pk(tb[0][0], xb0, nx); cmacc_rj_pk(tb[0][1], xb0, ny);
            cmacc_rj_pk(tb[1][0], xb1, nx); cmacc_rj_pk(tb[1][1], xb1, ny);
        }
        #pragma unroll
        for (int g = 0; g < 2; ++g) {
            *(v4f*)&TAT[(c0+g)*34 + r0] = cat(ta[0][g], ta[1][g]);
            *(v4f*)&TBT[(c0+g)*34 + r0] = cat(tb[0][g], tb[1][g]);
        }
    }
    __syncthreads();

    // ---- P4: A1 = TA @ LA^H, B1 = TB @ LB^H (conj(LA[c][k]) = CLA[k*32+c]) ----
    {
        v2f a1[2][2] = {}, b1[2][2] = {};
        #pragma unroll
        for (int k = 0; k < 32; ++k) {
            const v4f t  = *(const v4f*)&TAT[k*34 + r0];
            const v4f u  = *(const v4f*)&TBT[k*34 + r0];
            const v4f ca = *(const v4f*)&CLA[k*32 + c0];
            const v4f cb = *(const v4f*)&CLB[k*32 + c0];
            const v2f t0 = lo2(t), t1 = hi2(t), u0 = lo2(u), u1 = hi2(u);
            const v2f ca0 = lo2(ca), ca1 = hi2(ca), cb0 = lo2(cb), cb1 = hi2(cb);
            cmacc_pk(a1[0][0], t0, ca0); cmacc_pk(a1[0][1], t0, ca1);
            cmacc_pk(a1[1][0], t1, ca0); cmacc_pk(a1[1][1], t1, ca1);
            cmacc_pk(b1[0][0], u0, cb0); cmacc_pk(b1[0][1], u0, cb1);
            cmacc_pk(b1[1][0], u1, cb0); cmacc_pk(b1[1][1], u1, cb1);
        }
        #pragma unroll
        for (int p = 0; p < 2; ++p)
            #pragma unroll
            for (int g = 0; g < 2; ++g) {
                A1p[(r0+p)*33 + c0+g] = a1[p][g];
                B1p[(r0+p)*33 + c0+g] = b1[p][g];
            }
    }
    __syncthreads();

    // ---- P5a: 8 B-trace sums S[p][eps][del] = sum_{kb%2==p} B1[(eps<<4)^G(kb)][(del<<4)^G(kb)]
    if (tid < 8) {
        const int p = (tid >> 2) & 1, eps = (tid >> 1) & 1, del = tid & 1;
        v2f s = {0.f, 0.f};
        #pragma unroll
        for (int m = 0; m < 16; ++m) {
            const int kb = 2*m + p;
            const int g  = kb ^ (kb >> 1);
            s += B1p[((eps<<4)^g)*33 + ((del<<4)^g)];
        }
        Sarr[tid] = s;   // TAT region dead after P4
    }
    __syncthreads();

    // ---- P5b: N[r,c] = A1[G(r)][G(c)]*S[0][r&1][c&1] + A1[G(r)^24][G(c)^24]*S[1][r&1][c&1]
    {
        const int gr0 = r0 ^ (r0 >> 1), gr1 = (r0+1) ^ ((r0+1) >> 1);
        const int gc0 = c0 ^ (c0 >> 1), gc1 = (c0+1) ^ ((c0+1) >> 1);
        const v2f A00 = A1p[gr0*33 + gc0],        A01 = A1p[gr0*33 + gc1];
        const v2f A10 = A1p[gr1*33 + gc0],        A11 = A1p[gr1*33 + gc1];
        const v2f X00 = A1p[(gr0^24)*33 + (gc0^24)], X01 = A1p[(gr0^24)*33 + (gc1^24)];
        const v2f X10 = A1p[(gr1^24)*33 + (gc0^24)], X11 = A1p[(gr1^24)*33 + (gc1^24)];
        v2f n[2][2] = {};
        cmacc_pk(n[0][0], A00, Sarr[0]); cmacc_pk(n[0][0], X00, Sarr[4]);
        cmacc_pk(n[0][1], A01, Sarr[1]); cmacc_pk(n[0][1], X01, Sarr[5]);
        cmacc_pk(n[1][0], A10, Sarr[2]); cmacc_pk(n[1][0], X10, Sarr[6]);
        cmacc_pk(n[1][1], A11, Sarr[3]); cmacc_pk(n[1][1], X11, Sarr[7]);
        #pragma unroll
        for (int p = 0; p < 2; ++p)
            *(v4f*)&Np[(r0+p)*34 + c0] = cat(n[p][0], n[p][1]);   // CLA/CLB dead
    }
    __syncthreads();

    // ---- P6: TF = L2A @ N  (L2A[i][k] = conj(CL2A[k*32+i])) ----
    {
        v2f tf[2][2] = {};
        #pragma unroll
        for (int k = 0; k < 32; ++k) {
            const v4f x = *(const v4f*)&CL2A[k*32 + r0];
            const v4f m = *(const v4f*)&Np[k*34 + c0];
            const v2f x0 = lo2(x), x1 = hi2(x), m0 = lo2(m), m1 = hi2(m);
            cmacc_cj_pk(tf[0][0], x0, m0); cmacc_cj_pk(tf[0][1], x0, m1);
            cmacc_cj_pk(tf[1][0], x1, m0); cmacc_cj_pk(tf[1][1], x1, m1);
        }
        #pragma unroll
        for (int g = 0; g < 2; ++g)
            *(v4f*)&TFT[(c0+g)*34 + r0] = cat(tf[0][g], tf[1][g]);  // Sarr dead
    }
    __syncthreads();

    // ---- P7: R = TF @ L2A^H, store ----
    {
        v2f rr[2][2] = {};
        #pragma unroll
        for (int k = 0; k < 32; ++k) {
            const v4f t  = *(const v4f*)&TFT[k*34 + r0];
            const v4f c2 = *(const v4f*)&CL2A[k*32 + c0];
            const v2f t0 = lo2(t), t1 = hi2(t), c20 = lo2(c2), c21 = hi2(c2);
            cmacc_pk(rr[0][0], t0, c20); cmacc_pk(rr[0][1], t0, c21);
            cmacc_pk(rr[1][0], t1, c20); cmacc_pk(rr[1][1], t1, c21);
        }
        if (out_size >= 4096) {
            #pragma unroll
            for (int p = 0; p < 2; ++p)
                *(v4f*)&out[blk*2048 + (r0+p)*64 + 4*j0] = cat(rr[p][0], rr[p][1]);
        } else {
            #pragma unroll
            for (int p = 0; p < 2; ++p) {
                float2 v = { rr[p][0].x, rr[p][1].x };
                *(float2*)&out[blk*1024 + (r0+p)*32 + c0] = v;
            }
        }
    }
}

extern "C" void kernel_launch(void* const* d_in, const int* in_sizes, int n_in,
                              void* d_out, int out_size, void* d_ws, size_t ws_size,
                              hipStream_t stream) {
    const float* A = (const float*)d_in[0];   // inputA 32x32 fp32
    const float* B = (const float*)d_in[1];   // inputB 32x32 fp32
    const float* w = (const float*)d_in[2];   // weight 60 fp32
    float* out = (float*)d_out;
    qmutual_kernel<<<2, 256, 0, stream>>>(A, B, w, out, out_size);
}